// Round 5
// baseline (49.947 us; speedup 1.0000x reference)
//
#include <hip/hip_runtime.h>

// attn [B=64, N=1024, N=1024] f32. Per (b, k=1..1022): unbiased std of the
// k-th super-diagonal scaled by (N-k)/5; mean over k then b -> scalar.
//
// Pass 1 (grid NB*RCH, 256 thr): rows of a block share i mod RCH (RCH%4==0).
// Phase p=(-c) mod 4 (0->4) makes k=p+4t a 16B-aligned float4 window; thread
// t owns 4 fixed k's across all its rows. The i-loop is split per wave w
// (wave-uniform bounds, no divergence on the branch):
//   full phase  (i <= 768-p-256w):  UNGUARDED load + 8 FMA, unroll 8
//               -> 8 independent float4 loads in flight, no exec churn.
//   tail phase  (i <= 1023-p-256w): unguarded load (proven in-sample:
//               max addr = 1048830-1024*(p+256w) < 2^20), per-lane cndmask.
// Row 1023 has no valid k and is never read. Edge columns k=1..p-1: wave
// w==e, one row per lane + __shfl_xor reduce. Partials phase-relative at
// slot k-p (coalesced float4 stores); edges at 1024+k.
//
// Pass 2 (grid NB*4, 256 thr): reduce RCH chunk partials per (b,k), std
// formula, block reduce; last arriving block (device-scope counter, reset
// by pass 1) does a fixed-order final sum -> scalar. Deterministic.

#define NN 1024
#define NB 64
#define WSTRIDE 1032   // 1024 window slots + 3 edge slots + pad

template<int RCH>
__global__ __launch_bounds__(256) void diag_pass1(
    const float* __restrict__ attn, float* __restrict__ ws,
    unsigned int* __restrict__ counter) {
  const int b = blockIdx.x / RCH;
  const int c = blockIdx.x % RCH;
  const int t = threadIdx.x;
  if (blockIdx.x == 0 && t == 0)
    __hip_atomic_store(counter, 0u, __ATOMIC_RELAXED, __HIP_MEMORY_SCOPE_AGENT);

  int p = (4 - (c & 3)) & 3; if (p == 0) p = 4;   // k = p+4t is 16B-aligned
  const float* __restrict__ base = attn + ((size_t)b << 20);
  const int k0 = p + 4 * t;
  const int w  = t >> 6;                          // wave id 0..3
  const int q  = p + 256 * w;                     // wave's min k0

  // Wave-uniform bounds (floor division with negative clamp).
  const int df = 768 - q - c;                     // full:  i <= 768-q
  const int dt = 1023 - q - c;                    // any:   i <= 1023-q
  const int Mfull = (df >= 0) ? (df / RCH + 1) : 0;
  const int Mtot  = (dt >= 0) ? (dt / RCH + 1) : 0;

  const size_t rstride = (size_t)RCH * (NN + 1);
  const float* ptr = base + (size_t)c * (NN + 1) + k0;

  float s1x = 0.f, s1y = 0.f, s1z = 0.f, s1w = 0.f;
  float s2x = 0.f, s2y = 0.f, s2z = 0.f, s2w = 0.f;

  #pragma unroll 8
  for (int m = 0; m < Mfull; ++m) {               // pure: load + 8 FMA
    const float4 v = *reinterpret_cast<const float4*>(ptr);
    ptr += rstride;
    s1x += v.x; s2x += v.x * v.x;
    s1y += v.y; s2y += v.y * v.y;
    s1z += v.z; s2z += v.z * v.z;
    s1w += v.w; s2w += v.w * v.w;
  }
  for (int m = Mfull; m < Mtot; ++m) {            // tail: mask, no branch
    const int lim = NN - (c + RCH * m);           // wave-uniform per iter
    const float4 v = *reinterpret_cast<const float4*>(ptr);
    ptr += rstride;
    const float x0 = (k0     < lim) ? v.x : 0.f;
    const float x1 = (k0 + 1 < lim) ? v.y : 0.f;
    const float x2 = (k0 + 2 < lim) ? v.z : 0.f;
    const float x3 = (k0 + 3 < lim) ? v.w : 0.f;
    s1x += x0; s2x += x0 * x0;
    s1y += x1; s2y += x1 * x1;
    s1z += x2; s2z += x2 * x2;
    s1w += x3; s2w += x3 * x3;
  }

  float* __restrict__ w1 = ws + (size_t)blockIdx.x * (2 * WSTRIDE);
  float* __restrict__ w2 = w1 + WSTRIDE;
  *reinterpret_cast<float4*>(w1 + 4 * t) = make_float4(s1x, s1y, s1z, s1w);
  *reinterpret_cast<float4*>(w2 + 4 * t) = make_float4(s2x, s2y, s2z, s2w);

  // Edge columns k = 1..p-1: wave w handles column e=w, one row per lane.
  const int e = w;
  if (e >= 1 && e < p) {
    const int l = t & 63;
    float e1 = 0.f, e2 = 0.f;
    #pragma unroll
    for (int r = l; r < NN / RCH; r += 64) {
      const int i = c + RCH * r;
      if (i + e < NN) {                           // k=e valid iff i <= NN-1-e
        const float x = base[(size_t)i * (NN + 1) + e];
        e1 += x; e2 += x * x;
      }
    }
    #pragma unroll
    for (int s = 1; s < 64; s <<= 1) {
      e1 += __shfl_xor(e1, s);
      e2 += __shfl_xor(e2, s);
    }
    if (l == 0) {
      w1[1024 + e] = e1;
      w2[1024 + e] = e2;
    }
  }
}

template<int RCH>
__global__ __launch_bounds__(256) void diag_pass2(
    const float* __restrict__ ws, float* __restrict__ part,
    unsigned int* __restrict__ counter, float* __restrict__ out) {
  const int b  = blockIdx.x >> 2;
  const int kc = blockIdx.x & 3;
  const int t  = threadIdx.x;
  const int k  = kc * 256 + t;       // 0..1023; valid 1..1022

  float acc = 0.f;
  if (k >= 1 && k <= NN - 2) {
    float s1 = 0.f, s2 = 0.f;
    #pragma unroll
    for (int c = 0; c < RCH; ++c) {
      int p = (4 - (c & 3)) & 3; if (p == 0) p = 4;
      const float* __restrict__ w1 =
          ws + (size_t)(b * RCH + c) * (2 * WSTRIDE);
      const float* __restrict__ w2 = w1 + WSTRIDE;
      const int s = k - p;
      const int idx = (s >= 0) ? s : (1024 + k);   // window or edge slot
      s1 += w1[idx];
      s2 += w2[idx];
    }
    const float n = (float)(NN - k);
    const float mean = s1 / n;
    const float var = fmaxf(s2 - n * mean * mean, 0.f) / (n - 1.f);
    acc = sqrtf(var) * (n * 0.2f);   // std * (N-k)/5
  }

  __shared__ float red[256];
  red[t] = acc;
  __syncthreads();
  #pragma unroll
  for (int s = 128; s > 0; s >>= 1) {
    if (t < s) red[t] += red[t + s];
    __syncthreads();
  }

  __shared__ unsigned int amLast;
  if (t == 0) {
    __hip_atomic_store(&part[blockIdx.x], red[0],
                       __ATOMIC_RELEASE, __HIP_MEMORY_SCOPE_AGENT);
    const unsigned int old = __hip_atomic_fetch_add(
        counter, 1u, __ATOMIC_ACQ_REL, __HIP_MEMORY_SCOPE_AGENT);
    amLast = (old == gridDim.x - 1) ? 1u : 0u;
  }
  __syncthreads();
  if (amLast && t < 64) {            // one wave, fixed-order reduce
    float v = 0.f;
    #pragma unroll
    for (int j = 0; j < 4; ++j)
      v += __hip_atomic_load(&part[4 * t + j],
                             __ATOMIC_ACQUIRE, __HIP_MEMORY_SCOPE_AGENT);
    #pragma unroll
    for (int s = 32; s > 0; s >>= 1) v += __shfl_down(v, s);
    if (t == 0) out[0] = v * (1.0f / (1022.0f * 64.0f));
  }
}

template<int RCH>
static void launch_all(const float* attn, float* out, float* ws,
                       hipStream_t stream) {
  float* part = ws + (size_t)NB * RCH * 2 * WSTRIDE;          // 256 f32
  unsigned int* counter = (unsigned int*)(part + 256);        // 1 u32
  diag_pass1<RCH><<<NB * RCH, 256, 0, stream>>>(attn, ws, counter);
  diag_pass2<RCH><<<NB * 4, 256, 0, stream>>>(ws, part, counter, out);
}

extern "C" void kernel_launch(void* const* d_in, const int* in_sizes, int n_in,
                              void* d_out, int out_size, void* d_ws, size_t ws_size,
                              hipStream_t stream) {
  const float* attn = (const float*)d_in[0];
  float* out = (float*)d_out;
  float* ws = (float*)d_ws;

  const size_t need16 = ((size_t)NB * 16 * 2 * WSTRIDE + 256 + 1) * 4;
  const size_t need8  = ((size_t)NB * 8  * 2 * WSTRIDE + 256 + 1) * 4;

  if (ws_size >= need16)      launch_all<16>(attn, out, ws, stream);
  else if (ws_size >= need8)  launch_all<8>(attn, out, ws, stream);
  else                        launch_all<4>(attn, out, ws, stream);
}

// Round 6
// 49.052 us; speedup vs baseline: 1.0183x; 1.0183x over previous
//
#include <hip/hip_runtime.h>

// attn [B=64, N=1024, N=1024] f32. Per (b, k=1..1022): unbiased std of the
// k-th super-diagonal scaled by (N-k)/5; mean over k then b -> scalar.
//
// R6 = exact R2 structure (best so far, 43.3us) with ONE change: RCH 16->32
// (2048 blocks -> 8 blocks/CU, 32 waves/CU) + __launch_bounds__(256,8).
// Rationale: R3/R4/R5 all proved loop restructuring loses; masked loads are
// free. The residual gap to HBM roofline is latency exposure -> fix with TLP.
//
// Pass 1 (grid NB*RCH, 256 thr): rows share i mod RCH (RCH%4==0). Phase
// p=(-c) mod 4 (0->4) makes k=p+4t a 16B-aligned float4 window; thread t owns
// 4 fixed k's for all its rows (register accumulators, coalesced reads).
// Block-uniform 1024/RCH-iteration loop, per-lane guarded float4 load.
// Edge columns k=1..p-1 handled by threads 249..251 inline in the main loop.
// Partials phase-relative at slot k-p; edges at 1024+k.
//
// Pass 2 (grid NB*4, 256 thr): reduce RCH chunk partials per (b,k), std
// formula, block-reduce -> part[b*4+kc]. Pass 3 (1 block, 64 thr): scalar.

#define NN 1024
#define NB 64
#define WSTRIDE 1032   // 1024 window slots + 3 edge slots + pad (16B-aligned)

template<int RCH>
__global__ __launch_bounds__(256, 8) void diag_pass1(
    const float* __restrict__ attn, float* __restrict__ ws) {
  const int b = blockIdx.x / RCH;
  const int c = blockIdx.x % RCH;
  const int t = threadIdx.x;
  int p = (4 - (c & 3)) & 3; if (p == 0) p = 4;   // phase: k = p+4t aligned

  const float* __restrict__ base = attn + ((size_t)b << 20);
  const int k0 = p + 4 * t;

  float s1x = 0.f, s1y = 0.f, s1z = 0.f, s1w = 0.f;
  float s2x = 0.f, s2y = 0.f, s2z = 0.f, s2w = 0.f;
  float e1 = 0.f, e2 = 0.f;
  const int ek = t - 248;            // threads 249..251 own edge k = 1..3

  #pragma unroll 4
  for (int i = c; i < NN; i += RCH) {
    const int lim = NN - i;          // element (i,k) valid iff k < lim
    const float* __restrict__ rowd = base + (size_t)i * (NN + 1);
    if (k0 < lim) {
      const float4 v = *reinterpret_cast<const float4*>(rowd + k0);
      const float x0 = v.x;                          // k0 < lim guaranteed
      const float x1 = (k0 + 1 < lim) ? v.y : 0.f;
      const float x2 = (k0 + 2 < lim) ? v.z : 0.f;
      const float x3 = (k0 + 3 < lim) ? v.w : 0.f;
      s1x += x0; s2x += x0 * x0;
      s1y += x1; s2y += x1 * x1;
      s1z += x2; s2z += x2 * x2;
      s1w += x3; s2w += x3 * x3;
    }
    if (ek >= 1 && ek < p && ek < lim) {
      const float x = rowd[ek];
      e1 += x; e2 += x * x;
    }
  }

  float* __restrict__ w1 = ws + (size_t)blockIdx.x * (2 * WSTRIDE);
  float* __restrict__ w2 = w1 + WSTRIDE;
  *reinterpret_cast<float4*>(w1 + 4 * t) = make_float4(s1x, s1y, s1z, s1w);
  *reinterpret_cast<float4*>(w2 + 4 * t) = make_float4(s2x, s2y, s2z, s2w);
  if (ek >= 1 && ek < p) {           // read in pass 2 under the same condition
    w1[1024 + ek] = e1;
    w2[1024 + ek] = e2;
  }
}

template<int RCH>
__global__ __launch_bounds__(256) void diag_pass2(
    const float* __restrict__ ws, float* __restrict__ part) {
  const int b  = blockIdx.x >> 2;
  const int kc = blockIdx.x & 3;
  const int t  = threadIdx.x;
  const int k  = kc * 256 + t;       // 0..1023; valid 1..1022

  float acc = 0.f;
  if (k >= 1 && k <= NN - 2) {
    float s1 = 0.f, s2 = 0.f;
    #pragma unroll
    for (int c = 0; c < RCH; ++c) {
      int p = (4 - (c & 3)) & 3; if (p == 0) p = 4;
      const float* __restrict__ w1 =
          ws + (size_t)(b * RCH + c) * (2 * WSTRIDE);
      const float* __restrict__ w2 = w1 + WSTRIDE;
      const int s = k - p;
      const int idx = (s >= 0) ? s : (1024 + k);   // window or edge slot
      s1 += w1[idx];
      s2 += w2[idx];
    }
    const float n = (float)(NN - k);
    const float mean = s1 / n;
    const float var = fmaxf(s2 - n * mean * mean, 0.f) / (n - 1.f);
    acc = sqrtf(var) * (n * 0.2f);   // std * (N-k)/5
  }

  __shared__ float red[256];
  red[t] = acc;
  __syncthreads();
  #pragma unroll
  for (int s = 128; s > 0; s >>= 1) {
    if (t < s) red[t] += red[t + s];
    __syncthreads();
  }
  if (t == 0) part[blockIdx.x] = red[0];
}

__global__ __launch_bounds__(64) void diag_pass3(
    const float* __restrict__ part, float* __restrict__ out) {
  const int t = threadIdx.x;         // one wave; t = b
  float v = part[4 * t] + part[4 * t + 1] + part[4 * t + 2] + part[4 * t + 3];
  v *= (1.0f / 1022.0f);
  #pragma unroll
  for (int s = 32; s > 0; s >>= 1) v += __shfl_down(v, s);
  if (t == 0) out[0] = v * (1.0f / 64.0f);
}

template<int RCH>
static void launch_all(const float* attn, float* out, float* ws,
                       hipStream_t stream) {
  float* part = ws + (size_t)NB * RCH * 2 * WSTRIDE;   // NB*4 f32
  diag_pass1<RCH><<<NB * RCH, 256, 0, stream>>>(attn, ws);
  diag_pass2<RCH><<<NB * 4, 256, 0, stream>>>(ws, part);
  diag_pass3<<<1, 64, 0, stream>>>(part, out);
}

extern "C" void kernel_launch(void* const* d_in, const int* in_sizes, int n_in,
                              void* d_out, int out_size, void* d_ws, size_t ws_size,
                              hipStream_t stream) {
  const float* attn = (const float*)d_in[0];
  float* out = (float*)d_out;
  float* ws = (float*)d_ws;

  const size_t need32 = ((size_t)NB * 32 * 2 * WSTRIDE + NB * 4) * 4;
  const size_t need16 = ((size_t)NB * 16 * 2 * WSTRIDE + NB * 4) * 4;
  const size_t need8  = ((size_t)NB * 8  * 2 * WSTRIDE + NB * 4) * 4;

  if (ws_size >= need32)      launch_all<32>(attn, out, ws, stream);
  else if (ws_size >= need16) launch_all<16>(attn, out, ws, stream);
  else if (ws_size >= need8)  launch_all<8>(attn, out, ws, stream);
  else                        launch_all<4>(attn, out, ws, stream);
}

// Round 7
// 43.965 us; speedup vs baseline: 1.1361x; 1.1157x over previous
//
#include <hip/hip_runtime.h>

// attn [B=64, N=1024, N=1024] f32. Per (b, k=1..1022): unbiased std of the
// k-th super-diagonal scaled by (N-k)/5; mean over k then b -> scalar.
//
// R7: pass 1 is EXACTLY R2's (best, 43.3us). Only change: pass 2 rebuilt for
// occupancy. R2/R6 slope showed pass2 ~ 0.36us*RCH (~6us @RCH16) because it
// ran 256 blocks = 4 waves/CU (12.5% occ) with RCH serial scattered loads.
// New pass 2: grid NB*16=1024 blocks x 256 thr; block (b,kg) covers 64 k's;
// thread = (kk, cg): sums chunks c = cg, cg+4, ... (p = phase(c) constant per
// thread since c = cg mod 4), LDS-reduce over cg, std on wave 0, wave-reduce
// -> part[1024]. Pass 3: one block sums 1024 parts.
//
// Pass 1 (grid NB*RCH, 256 thr): rows share i mod RCH. Phase p=(-c) mod 4
// (0->4) makes k=p+4t a 16B-aligned float4 window; thread t owns 4 fixed k's
// (register accumulators, coalesced reads). Per-lane guarded float4 load.
// Edge columns k=1..p-1 by threads 249..251 inline. Partials at slot k-p;
// edges at 1024+k.

#define NN 1024
#define NB 64
#define WSTRIDE 1032   // 1024 window slots + 3 edge slots + pad (16B-aligned)

template<int RCH>
__global__ __launch_bounds__(256) void diag_pass1(
    const float* __restrict__ attn, float* __restrict__ ws) {
  const int b = blockIdx.x / RCH;
  const int c = blockIdx.x % RCH;
  const int t = threadIdx.x;
  int p = (4 - (c & 3)) & 3; if (p == 0) p = 4;   // phase: k = p+4t aligned

  const float* __restrict__ base = attn + ((size_t)b << 20);
  const int k0 = p + 4 * t;

  float s1x = 0.f, s1y = 0.f, s1z = 0.f, s1w = 0.f;
  float s2x = 0.f, s2y = 0.f, s2z = 0.f, s2w = 0.f;
  float e1 = 0.f, e2 = 0.f;
  const int ek = t - 248;            // threads 249..251 own edge k = 1..3

  #pragma unroll 4
  for (int i = c; i < NN; i += RCH) {
    const int lim = NN - i;          // element (i,k) valid iff k < lim
    const float* __restrict__ rowd = base + (size_t)i * (NN + 1);
    if (k0 < lim) {
      const float4 v = *reinterpret_cast<const float4*>(rowd + k0);
      const float x0 = v.x;                          // k0 < lim guaranteed
      const float x1 = (k0 + 1 < lim) ? v.y : 0.f;
      const float x2 = (k0 + 2 < lim) ? v.z : 0.f;
      const float x3 = (k0 + 3 < lim) ? v.w : 0.f;
      s1x += x0; s2x += x0 * x0;
      s1y += x1; s2y += x1 * x1;
      s1z += x2; s2z += x2 * x2;
      s1w += x3; s2w += x3 * x3;
    }
    if (ek >= 1 && ek < p && ek < lim) {
      const float x = rowd[ek];
      e1 += x; e2 += x * x;
    }
  }

  float* __restrict__ w1 = ws + (size_t)blockIdx.x * (2 * WSTRIDE);
  float* __restrict__ w2 = w1 + WSTRIDE;
  *reinterpret_cast<float4*>(w1 + 4 * t) = make_float4(s1x, s1y, s1z, s1w);
  *reinterpret_cast<float4*>(w2 + 4 * t) = make_float4(s2x, s2y, s2z, s2w);
  if (ek >= 1 && ek < p) {           // read in pass 2 under the same condition
    w1[1024 + ek] = e1;
    w2[1024 + ek] = e2;
  }
}

// Block (b, kg): k = kg*64 + kk, kk = t&63; cg = t>>6 sums c = cg, cg+4, ...
template<int RCH>
__global__ __launch_bounds__(256) void diag_pass2(
    const float* __restrict__ ws, float* __restrict__ part) {
  const int b  = blockIdx.x >> 4;
  const int kg = blockIdx.x & 15;
  const int t  = threadIdx.x;
  const int kk = t & 63;
  const int cg = t >> 6;             // 0..3, = c & 3 for this thread's chunks
  const int k  = kg * 64 + kk;       // 0..1023

  int p = (4 - cg) & 3; if (p == 0) p = 4;        // phase for c = cg (mod 4)
  const int idx = (k >= p) ? (k - p) : (1024 + k); // slot, same for all c here

  float s1 = 0.f, s2 = 0.f;
  #pragma unroll
  for (int c = cg; c < RCH; c += 4) {
    const float* __restrict__ w1 = ws + (size_t)(b * RCH + c) * (2 * WSTRIDE);
    s1 += w1[idx];
    s2 += w1[WSTRIDE + idx];
  }

  __shared__ float r1[256], r2[256];
  r1[t] = s1; r2[t] = s2;
  __syncthreads();
  if (t < 128) { r1[t] += r1[t + 128]; r2[t] += r2[t + 128]; }
  __syncthreads();
  if (t < 64) {
    s1 = r1[t] + r1[t + 64];
    s2 = r2[t] + r2[t + 64];
    float acc = 0.f;
    if (k >= 1 && k <= NN - 2) {
      const float n = (float)(NN - k);
      const float mean = s1 / n;
      const float var = fmaxf(s2 - n * mean * mean, 0.f) / (n - 1.f);
      acc = sqrtf(var) * (n * 0.2f);               // std * (N-k)/5
    }
    #pragma unroll
    for (int s = 32; s > 0; s >>= 1) acc += __shfl_down(acc, s);
    if (t == 0) part[blockIdx.x] = acc;
  }
}

__global__ __launch_bounds__(256) void diag_pass3(
    const float* __restrict__ part, float* __restrict__ out) {
  const int t = threadIdx.x;
  float v = part[t] + part[t + 256] + part[t + 512] + part[t + 768];
  __shared__ float red[256];
  red[t] = v;
  __syncthreads();
  #pragma unroll
  for (int s = 128; s > 0; s >>= 1) {
    if (t < s) red[t] += red[t + s];
    __syncthreads();
  }
  if (t == 0) out[0] = red[0] * (1.0f / (1022.0f * 64.0f));
}

template<int RCH>
static void launch_all(const float* attn, float* out, float* ws,
                       hipStream_t stream) {
  float* part = ws + (size_t)NB * RCH * 2 * WSTRIDE;   // 1024 f32
  diag_pass1<RCH><<<NB * RCH, 256, 0, stream>>>(attn, ws);
  diag_pass2<RCH><<<NB * 16, 256, 0, stream>>>(ws, part);
  diag_pass3<<<1, 256, 0, stream>>>(part, out);
}

extern "C" void kernel_launch(void* const* d_in, const int* in_sizes, int n_in,
                              void* d_out, int out_size, void* d_ws, size_t ws_size,
                              hipStream_t stream) {
  const float* attn = (const float*)d_in[0];
  float* out = (float*)d_out;
  float* ws = (float*)d_ws;

  const size_t need16 = ((size_t)NB * 16 * 2 * WSTRIDE + 1024) * 4;
  const size_t need8  = ((size_t)NB * 8  * 2 * WSTRIDE + 1024) * 4;

  if (ws_size >= need16)      launch_all<16>(attn, out, ws, stream);
  else if (ws_size >= need8)  launch_all<8>(attn, out, ws, stream);
  else                        launch_all<4>(attn, out, ws, stream);
}

// Round 8
// 40.901 us; speedup vs baseline: 1.2212x; 1.0749x over previous
//
#include <hip/hip_runtime.h>

// attn [B=64, N=1024, N=1024] f32. Per (b, k=1..1022): unbiased std of the
// k-th super-diagonal scaled by (N-k)/5; mean over k then b -> scalar.
//
// R8: balanced pass 1 ("complementary quad pairing"). R2's triangular layout
// decays from 48KB to 9KB useful bytes in flight per CU (waves with big k0
// finish early) -> 3.5 TB/s. Here thread t owns quad k0=p+4t AND quad
// 255-t; trip counts sum to ~64, each quad's row range split half/half
// between owner and mirror. Every load is unconditional: phase alignment
// (k0 = p+4t with rows i = c+16m, (i+k0) mod 4 == 0..) makes every quad
// row-wise all-or-nothing valid -> NO partial rows exist. All waves dense
// for ~32 iterations -> concurrency stays flat.
//
// ws per block (4 sections x W): [A_sum][B_sum][A_sq][B_sq]; quad q's
// partials at slot 4q (A = first-half rows, B = second-half rows); edge
// columns k=1..p-1 at slot 1024+k in A (B zeroed). Pass 2 sums A+B over
// chunks; pass 3 reduces 1024 parts.

#define NN 1024
#define NB 64
#define RCH 16
#define W 1032   // section stride: 1024 slots + 3 edge + pad

__global__ __launch_bounds__(256) void diag_pass1(
    const float* __restrict__ attn, float* __restrict__ ws) {
  const int b = blockIdx.x >> 4;    // / RCH
  const int c = blockIdx.x & 15;    // % RCH
  const int t = threadIdx.x;
  int p = (4 - (c & 3)) & 3; if (p == 0) p = 4;   // k = p+4t is 16B-aligned

  const float* __restrict__ base = attn + ((size_t)b << 20);
  const float* __restrict__ rowc = base + (size_t)c * (NN + 1);
  const size_t stride = (size_t)RCH * (NN + 1);

  // Quad A = t: rows m in [0, SaA)  (first half of its valid range)
  const int k0a = p + 4 * t;
  const int dfA = 1020 - c - p - 4 * t;           // full-valid iff 16m <= dfA
  const int TfA = (dfA >= 0) ? ((dfA >> 4) + 1) : 0;
  const int SaA = (TfA + 1) >> 1;

  float a1x=0.f,a1y=0.f,a1z=0.f,a1w=0.f,a2x=0.f,a2y=0.f,a2z=0.f,a2w=0.f;
  {
    const float* ptr = rowc + k0a;
    #pragma unroll 4
    for (int m = 0; m < SaA; ++m) {
      const float4 v = *reinterpret_cast<const float4*>(ptr + (size_t)m * stride);
      a1x += v.x; a2x += v.x * v.x;
      a1y += v.y; a2y += v.y * v.y;
      a1z += v.z; a2z += v.z * v.z;
      a1w += v.w; a2w += v.w * v.w;
    }
  }

  // Quad B = 255-t: rows m in [SaB, TfB)  (second half of ITS valid range)
  const int qB  = 255 - t;
  const int k0b = p + 4 * qB;
  const int dfB = 4 * t - c - p;                  // = 1020-c-p-4*qB
  const int TfB = (dfB >= 0) ? ((dfB >> 4) + 1) : 0;
  const int SaB = (TfB + 1) >> 1;

  float b1x=0.f,b1y=0.f,b1z=0.f,b1w=0.f,b2x=0.f,b2y=0.f,b2z=0.f,b2w=0.f;
  {
    const float* ptr = rowc + k0b;
    #pragma unroll 4
    for (int m = SaB; m < TfB; ++m) {
      const float4 v = *reinterpret_cast<const float4*>(ptr + (size_t)m * stride);
      b1x += v.x; b2x += v.x * v.x;
      b1y += v.y; b2y += v.y * v.y;
      b1z += v.z; b2z += v.z * v.z;
      b1w += v.w; b2w += v.w * v.w;
    }
  }

  float* __restrict__ wsA1 = ws + (size_t)blockIdx.x * (4 * W);
  float* __restrict__ wsB1 = wsA1 + W;
  float* __restrict__ wsA2 = wsA1 + 2 * W;
  float* __restrict__ wsB2 = wsA1 + 3 * W;

  *reinterpret_cast<float4*>(wsA1 + 4 * t)  = make_float4(a1x,a1y,a1z,a1w);
  *reinterpret_cast<float4*>(wsA2 + 4 * t)  = make_float4(a2x,a2y,a2z,a2w);
  *reinterpret_cast<float4*>(wsB1 + 4 * qB) = make_float4(b1x,b1y,b1z,b1w);
  *reinterpret_cast<float4*>(wsB2 + 4 * qB) = make_float4(b2x,b2y,b2z,b2w);

  // Edge columns k = 1..p-1: wave w==e, one row per lane + shfl reduce.
  const int e = t >> 6;
  if (e >= 1 && e < p) {
    const int l = t & 63;
    const int i = c + RCH * l;                    // NN/RCH = 64 rows exactly
    float x = 0.f;
    if (i + e < NN) x = base[(size_t)i * (NN + 1) + e];
    float e1 = x, e2 = x * x;
    #pragma unroll
    for (int s = 1; s < 64; s <<= 1) {
      e1 += __shfl_xor(e1, s);
      e2 += __shfl_xor(e2, s);
    }
    if (l == 0) {
      wsA1[1024 + e] = e1;  wsA2[1024 + e] = e2;
      wsB1[1024 + e] = 0.f; wsB2[1024 + e] = 0.f;
    }
  }
}

// Block (b, kg): k = kg*64 + kk; cg = t>>6 sums chunks c = cg, cg+4, ...
__global__ __launch_bounds__(256) void diag_pass2(
    const float* __restrict__ ws, float* __restrict__ part) {
  const int b  = blockIdx.x >> 4;
  const int kg = blockIdx.x & 15;
  const int t  = threadIdx.x;
  const int kk = t & 63;
  const int cg = t >> 6;
  const int k  = kg * 64 + kk;

  int p = (4 - cg) & 3; if (p == 0) p = 4;        // phase for c = cg (mod 4)
  const int idx = (k >= p) ? (k - p) : (1024 + k);

  float s1 = 0.f, s2 = 0.f;
  #pragma unroll
  for (int c = cg; c < RCH; c += 4) {
    const float* __restrict__ w0 = ws + (size_t)(b * RCH + c) * (4 * W);
    s1 += w0[idx] + w0[W + idx];
    s2 += w0[2 * W + idx] + w0[3 * W + idx];
  }

  __shared__ float r1[256], r2[256];
  r1[t] = s1; r2[t] = s2;
  __syncthreads();
  if (t < 128) { r1[t] += r1[t + 128]; r2[t] += r2[t + 128]; }
  __syncthreads();
  if (t < 64) {
    s1 = r1[t] + r1[t + 64];
    s2 = r2[t] + r2[t + 64];
    float acc = 0.f;
    if (k >= 1 && k <= NN - 2) {
      const float n = (float)(NN - k);
      const float mean = s1 / n;
      const float var = fmaxf(s2 - n * mean * mean, 0.f) / (n - 1.f);
      acc = sqrtf(var) * (n * 0.2f);              // std * (N-k)/5
    }
    #pragma unroll
    for (int s = 32; s > 0; s >>= 1) acc += __shfl_down(acc, s);
    if (t == 0) part[blockIdx.x] = acc;
  }
}

__global__ __launch_bounds__(256) void diag_pass3(
    const float* __restrict__ part, float* __restrict__ out) {
  const int t = threadIdx.x;
  float v = part[t] + part[t + 256] + part[t + 512] + part[t + 768];
  __shared__ float red[256];
  red[t] = v;
  __syncthreads();
  #pragma unroll
  for (int s = 128; s > 0; s >>= 1) {
    if (t < s) red[t] += red[t + s];
    __syncthreads();
  }
  if (t == 0) out[0] = red[0] * (1.0f / (1022.0f * 64.0f));
}

extern "C" void kernel_launch(void* const* d_in, const int* in_sizes, int n_in,
                              void* d_out, int out_size, void* d_ws, size_t ws_size,
                              hipStream_t stream) {
  const float* attn = (const float*)d_in[0];
  float* out = (float*)d_out;
  float* ws = (float*)d_ws;

  float* part = ws + (size_t)NB * RCH * 4 * W;    // 1024 f32 (~17 MB total)

  diag_pass1<<<NB * RCH, 256, 0, stream>>>(attn, ws);
  diag_pass2<<<NB * 16, 256, 0, stream>>>(ws, part);
  diag_pass3<<<1, 256, 0, stream>>>(part, out);
}